// Round 7
// baseline (156.004 us; speedup 1.0000x reference)
//
#include <hip/hip_runtime.h>
#include <hip/hip_bf16.h>

#define N 8192
#define D 256
#define NC 64
#define NQ 16        // col chunks (512 cols per sim block)
#define NT 16        // 32-col tiles per block
// sim = dot/0.5 = 2*dot; rows normalized -> fixed shift 2.0 replaces row-max
// (log-sum-exp shift invariance). Positive-pair dot sum handled analytically:
//   sum_pos s = 2*(sum_c ||S_c||^2 - N),  S_c = sum_{lab=c} e_i  (bf16 inputs,
//   fp32 accumulate -- same rounding class as the MFMA dots, r4-verified).
// So the O(N^2) kernel computes ONLY Z_i = sum_j exp(s_ij - 2): epilogue is
// fma + exp2 + add per element (VALU no longer co-binding with MFMA).

typedef __attribute__((ext_vector_type(8))) short bf16x8;
typedef __attribute__((ext_vector_type(4))) float f32x4;

#define K1 2.8853900817779268f   // 2*log2(e)
#define K2 (-2.8853900817779268f)

__device__ inline unsigned short f2bf(float x) {
    __hip_bfloat16 h = __float2bfloat16(x);
    return *reinterpret_cast<unsigned short*>(&h);
}

__device__ inline float fast_exp2(float t) {
#if __has_builtin(__builtin_amdgcn_exp2f)
    return __builtin_amdgcn_exp2f(t);
#else
    return __expf(t * 0.69314718056f);
#endif
}

__device__ inline float bf2f(unsigned short u) {
    unsigned v = ((unsigned)u) << 16;
    return __builtin_bit_cast(float, v);
}

// ---------------- kernel 1: fp32 -> bf16 convert + zero accumulators ----------------
__global__ void convert_kernel(const float4* __restrict__ E4, ushort4* __restrict__ Ebf4,
                               float* __restrict__ nd, int* __restrict__ histg) {
    int i = blockIdx.x * blockDim.x + threadIdx.x;
    if (i < (N * D) / 4) {
        float4 v = E4[i];
        ushort4 o;
        o.x = f2bf(v.x); o.y = f2bf(v.y); o.z = f2bf(v.z); o.w = f2bf(v.w);
        Ebf4[i] = o;
    }
    if (i < 2) nd[i] = 0.0f;
    if (i < NC) histg[i] = 0;
}

// ---------------- kernel 2: atomic-free class sums + histogram ----------------
// 64 blocks x 256 thr; block b owns rows [b*128, +128). Thread t owns
// (class c = t>>2, dim quarter dseg = t&3): scans its 128 rows, accumulates
// matching rows' 64 dims in REGISTERS (no LDS RMW chains, no global atomics),
// writes one 64-fp32 slice of Spart[b]. Per-class count -> 64 global atomics/block.
__global__ __launch_bounds__(256)
void classsum_kernel(const __hip_bfloat16* __restrict__ Ebf,
                     const int* __restrict__ labels,
                     float* __restrict__ Spart, int* __restrict__ histg) {
    const int t = threadIdx.x;
    const int c = t >> 2;
    const int dseg = t & 3;
    const int b = blockIdx.x;
    float acc[64];
#pragma unroll
    for (int k = 0; k < 64; ++k) acc[k] = 0.0f;
    int cnt = 0;
    for (int r = 0; r < 128; ++r) {
        int i = b * 128 + r;
        if (labels[i] == c) {
            ++cnt;
            const bf16x8* rp = reinterpret_cast<const bf16x8*>(
                (const unsigned short*)Ebf + (size_t)i * D + dseg * 64);
#pragma unroll
            for (int v8 = 0; v8 < 8; ++v8) {
                bf16x8 v = rp[v8];
#pragma unroll
                for (int e = 0; e < 8; ++e)
                    acc[v8 * 8 + e] += bf2f((unsigned short)v[e]);
            }
        }
    }
    float* dst = Spart + (size_t)b * (NC * D) + c * D + dseg * 64;
#pragma unroll
    for (int k = 0; k < 64; ++k) dst[k] = acc[k];
    if (dseg == 0 && cnt) atomicAdd(&histg[c], cnt);
}

// ---------------- kernel 3: Z-only fused sim + exp-sum ----------------
// 512 blocks x 256 thr (4 waves), 2 blocks/CU, all co-resident. Block: rows
// [rp*256,+256) x cols [q*512,+512) as 16 tiles of 32 cols x full K=256.
// A-frags register-PINNED via asm "+v" (prevents remat / per-tile reload).
// B slab 16 KB/tile in FOUR rolling LDS buffers (64 KB), staged via
// global_load_lds(16B): linear dest + inverse-swizzled source (rule #21;
// measured zero bank conflicts r2-r6). Depth-3 prefetch, ONE s_barrier/tile,
// uniform counted vmcnt(8). Ledger (per wave; vmcnt retires IN ORDER, m135):
// loop has NO other VMEM -- at tile t outstanding = stage(t+1) 4 + stage(t+2) 4;
// vmcnt(8) => stage(t) (and at t=0 the A/label prologue loads) landed.
// stage(t+3) writes buf (t+3)&3 = buf(t-1), whose readers are 1+ barriers past.
__global__ __launch_bounds__(256, 2)
void sim_kernel(const __hip_bfloat16* __restrict__ Ebf, float* __restrict__ Zp) {
    __shared__ unsigned char Bsh[4 * 16384];   // 64 KB

    const int tid  = threadIdx.x;
    const int lane = tid & 63;
    const int wid  = tid >> 6;        // 0..3
    const int l15  = lane & 15;
    const int l4   = lane >> 4;       // 0..3
    const int rpnl = blockIdx.x >> 4; // row panel 0..31
    const int q    = blockIdx.x & 15; // col chunk 0..15
    const char* eb = (const char*)Ebf;

    // A fragments: row = l15, k-seg = l4; 4 row-groups x 8 kg x 16B = 128 VGPRs
    bf16x8 a[4][8];
#pragma unroll
    for (int rg = 0; rg < 4; ++rg) {
        int row = rpnl * 256 + wid * 64 + rg * 16 + l15;
        const char* ap = eb + (size_t)row * 512 + l4 * 16;
#pragma unroll
        for (int kg = 0; kg < 8; ++kg)
            a[rg][kg] = *reinterpret_cast<const bf16x8*>(ap + kg * 64);
    }
    // pin A in arch VGPRs: forbids rematerialization/spill-reload in the loop
#pragma unroll
    for (int rg = 0; rg < 4; ++rg)
#pragma unroll
        for (int kg = 0; kg < 8; ++kg)
            asm volatile("" : "+v"(a[rg][kg]));

    // lane-only swizzled ds_read offset (zero-conflict, verified r2-r6)
    const unsigned laneSwz = (unsigned)(l15 * 64 + ((l4 ^ ((l15 >> 1) & 3)) << 4));

    auto stage = [&](int t, int buf) {
        const unsigned bufb = (unsigned)buf * 16384u;
#pragma unroll
        for (int m = 0; m < 4; ++m) {
            int c = wid * 4 + m;                 // 16 chunks of 1 KB
            int kg = c >> 1, colblk = c & 1;
            int colLocal = colblk * 16 + (lane >> 2);
            int seg = (lane & 3) ^ ((colLocal >> 1) & 3);   // inverse swizzle on src
            const char* src = eb + (size_t)(q * 512 + t * 32 + colLocal) * 512
                            + kg * 64 + seg * 16;
            __builtin_amdgcn_global_load_lds(
                (const __attribute__((address_space(1))) void*)src,
                (__attribute__((address_space(3))) void*)
                    (Bsh + bufb + kg * 2048u + colblk * 1024u),
                16, 0, 0);
        }
    };

    float zacc[4][4];
#pragma unroll
    for (int rg = 0; rg < 4; ++rg)
#pragma unroll
        for (int r = 0; r < 4; ++r) zacc[rg][r] = 0.0f;

    stage(0, 0);
    stage(1, 1);
    stage(2, 2);

    for (int t = 0; t < NT; ++t) {
        asm volatile("s_waitcnt vmcnt(8)" ::: "memory");
        __builtin_amdgcn_s_barrier();
        if (t + 3 < NT) stage(t + 3, (t + 3) & 3);

        const unsigned bufb = (unsigned)(t & 3) * 16384u;
        f32x4 acc[4][2];
#pragma unroll
        for (int rg = 0; rg < 4; ++rg) {
            acc[rg][0] = (f32x4){0.f, 0.f, 0.f, 0.f};
            acc[rg][1] = (f32x4){0.f, 0.f, 0.f, 0.f};
        }

        __builtin_amdgcn_s_setprio(1);
#pragma unroll
        for (int kg = 0; kg < 8; ++kg) {
            bf16x8 b0 = *reinterpret_cast<const bf16x8*>(Bsh + bufb + kg * 2048 + laneSwz);
            bf16x8 b1 = *reinterpret_cast<const bf16x8*>(Bsh + bufb + kg * 2048 + 1024 + laneSwz);
#pragma unroll
            for (int rg = 0; rg < 4; ++rg) {
                acc[rg][0] = __builtin_amdgcn_mfma_f32_16x16x32_bf16(a[rg][kg], b0, acc[rg][0], 0, 0, 0);
                acc[rg][1] = __builtin_amdgcn_mfma_f32_16x16x32_bf16(a[rg][kg], b1, acc[rg][1], 0, 0, 0);
            }
        }
        __builtin_amdgcn_s_setprio(0);

        // slim epilogue: Z += exp2(K1*dot + K2)  (= exp(2*dot - 2))
#pragma unroll
        for (int rg = 0; rg < 4; ++rg)
#pragma unroll
            for (int r = 0; r < 4; ++r)
                zacc[rg][r] += fast_exp2(__builtin_fmaf(acc[rg][0][r], K1, K2))
                             + fast_exp2(__builtin_fmaf(acc[rg][1][r], K1, K2));
    }

    // 16-lane shfl reduce over cols, then plain (atomic-free) partial store
#pragma unroll
    for (int rg = 0; rg < 4; ++rg)
#pragma unroll
        for (int r = 0; r < 4; ++r) {
            float z = zacc[rg][r];
#pragma unroll
            for (int m = 1; m <= 8; m <<= 1) z += __shfl_xor(z, m, 64);
            if (l15 == 0) {
                int row = rpnl * 256 + wid * 64 + rg * 16 + l4 * 4 + r;
                Zp[q * N + row] = z;
            }
        }
}

// ---------------- kernel 4: finalize (parallel: 32 blocks) ----------------
// num = sum_i c_i*(2 + ln(Z_i - 1)) - 2*(sum_c ||S_c||^2) + 2N;  den = sum_i c_i
__global__ __launch_bounds__(256)
void finalize_kernel(const float* __restrict__ Zp, const float* __restrict__ Spart,
                     const int* __restrict__ labels, const int* __restrict__ histg,
                     float* __restrict__ nd) {
    __shared__ float s0[256], s1[256];
    const int t = threadIdx.x;
    const int b = blockIdx.x;

    // per-row slice: row i = b*256 + t
    int i = b * 256 + t;
    float z = 0.0f;
#pragma unroll
    for (int qq = 0; qq < NQ; ++qq) z += Zp[qq * N + i];
    z -= 1.0f;                               // remove diag exp(s_ii-2) ~= 1
    float c = (float)(histg[labels[i]] - 1);
    float num = c * (2.0f + __logf(z));
    float den = c;

    // class-sum-square slice: (c,d) pairs [b*512, +512), 2 per thread
#pragma unroll
    for (int u = 0; u < 2; ++u) {
        int pidx = b * 512 + t * 2 + u;
        float s = 0.0f;
        for (int bb = 0; bb < 64; ++bb) s += Spart[(size_t)bb * (NC * D) + pidx];
        num -= 2.0f * s * s;
    }
    if (b == 0 && t == 0) num += 2.0f * (float)N;   // add back sum_i dot_ii ~= N (x2)

    s0[t] = num; s1[t] = den;
    __syncthreads();
    for (int s = 128; s > 0; s >>= 1) {
        if (t < s) { s0[t] += s0[t + s]; s1[t] += s1[t + s]; }
        __syncthreads();
    }
    if (t == 0) { atomicAdd(&nd[0], s0[0]); atomicAdd(&nd[1], s1[0]); }
}

// ---------------- kernel 5: scalar divide ----------------
__global__ void div_kernel(const float* __restrict__ nd, float* __restrict__ out) {
    out[0] = nd[0] / nd[1];
}

extern "C" void kernel_launch(void* const* d_in, const int* in_sizes, int n_in,
                              void* d_out, int out_size, void* d_ws, size_t ws_size,
                              hipStream_t stream) {
    const float* emb  = (const float*)d_in[0];
    const int* labels = (const int*)d_in[1];
    float* out = (float*)d_out;

    char* ws = (char*)d_ws;
    __hip_bfloat16* Ebf = (__hip_bfloat16*)ws;               // 4 MB
    float* Zp    = (float*)(ws + (size_t)N * D * 2);         // 16x8192 fp32 = 512 KB
    float* Spart = Zp + NQ * N;                              // 64x16384 fp32 = 4 MB
    float* nd    = Spart + 64 * (NC * D);                    // 8 B
    int*   histg = (int*)(nd + 2);                           // 256 B

    convert_kernel<<<(N * D / 4 + 255) / 256, 256, 0, stream>>>(
        (const float4*)emb, (ushort4*)Ebf, nd, histg);
    classsum_kernel<<<64, 256, 0, stream>>>(Ebf, labels, Spart, histg);
    sim_kernel<<<512, 256, 0, stream>>>(Ebf, Zp);
    finalize_kernel<<<32, 256, 0, stream>>>(Zp, Spart, labels, histg, nd);
    div_kernel<<<1, 1, 0, stream>>>(nd, out);
}